// Round 9
// baseline (998.387 us; speedup 1.0000x reference)
//
#include <hip/hip_runtime.h>
#include <hip/hip_bf16.h>
#include <cstdio>
#include <cstdint>

#define BB 8
#define NN 4096
#define FF 64

typedef __attribute__((ext_vector_type(8))) short bf16x8;
typedef __attribute__((ext_vector_type(4))) float f32x4;

__device__ __forceinline__ unsigned short f2bf(float f){
  unsigned int u = __float_as_uint(f);
  u += 0x7FFFu + ((u >> 16) & 1u);           // round-to-nearest-even
  return (unsigned short)(u >> 16);
}

__device__ __forceinline__ float leaky01(float x){ return x > 0.f ? x : 0.01f * x; }

// ================= fragment-order layouts =================
// A:  At[bid][t(64)][kk(2)][mi(2)][l(64)][j(8)]  (elems; frag=512 elems=1KB)
//     element = A[b][m0 + mi*16 + (l&15)][t*64 + kk*32 + (l>>4)*8 + j]
// B:  Bt[b][ct(8)][t(64)][kk(2)][l(64)][j(8)]
//     element = scale * H[row = t*64 + kk*32 + (l>>4)*8 + j][col = ct*16 + (l&15)]
//     (ct 0..3 = gcn half / cols 0..63 ; ct 4..7 = scat half)

// ---------------- pass 0: fp32 adj -> fragment-order bf16 A + row sums ----------------
__global__ __launch_bounds__(256) void k_convert(const float* __restrict__ adj,
    unsigned short* __restrict__ At, float* __restrict__ dinv, float* __restrict__ dsq)
{
  __shared__ unsigned short lt[32][264];     // 264*2B = 528 = 66*8 -> 8B-aligned rows
  const int bid = blockIdx.x;                // 1024 blocks; b = bid&7 (XCD-aligned)
  const int b = bid & 7, mt = bid >> 3, m0 = mt * 32;
  const int tid = threadIdx.x;
  const int w = tid >> 6;
  float rsum[8];
  #pragma unroll
  for (int i = 0; i < 8; ++i) rsum[i] = 0.f;

  unsigned short* dstb = At + (size_t)bid * 131072;
  for (int cc = 0; cc < 16; ++cc){
    // read phase: coalesced fp32, 32 rows x 256 cols
    #pragma unroll
    for (int rep = 0; rep < 8; ++rep){
      int idx = rep * 256 + tid;
      int rr = idx >> 6, c4 = (idx & 63) << 2;
      float4 v = *(const float4*)(adj + ((size_t)b * NN + m0 + rr) * NN + cc * 256 + c4);
      rsum[rep] += (v.x + v.y) + (v.z + v.w);
      *(ushort4*)&lt[rr][c4] = make_ushort4(f2bf(v.x), f2bf(v.y), f2bf(v.z), f2bf(v.w));
    }
    __syncthreads();
    // write phase: fragment-order, fully coalesced (8B per thread per it)
    #pragma unroll
    for (int it = 0; it < 8; ++it){
      int idx = it * 256 + tid;
      int half = idx & 1, l = (idx >> 1) & 63, mi = (idx >> 7) & 1,
          kk = (idx >> 8) & 1, tt = (idx >> 9) & 3;
      int row = mi * 16 + (l & 15);
      int kloc = tt * 64 + kk * 32 + ((l >> 4) << 3) + half * 4;
      ushort4 v = *(const ushort4*)&lt[row][kloc];
      *(ushort4*)(dstb + (size_t)(cc * 4 + tt) * 2048 + (kk * 2 + mi) * 512 + (l << 3) + half * 4) = v;
    }
    __syncthreads();
  }
  #pragma unroll
  for (int rep = 0; rep < 8; ++rep){
    float s = rsum[rep];
    s += __shfl_xor(s, 1);  s += __shfl_xor(s, 2);  s += __shfl_xor(s, 4);
    s += __shfl_xor(s, 8);  s += __shfl_xor(s, 16); s += __shfl_xor(s, 32);
    if ((tid & 63) == 0){
      int row = rep * 4 + w;
      dinv[(size_t)b * NN + m0 + row] = 1.0f / s;
      dsq [(size_t)b * NN + m0 + row] = 1.0f / sqrtf(s + 1.0f);
    }
  }
}

// ---------------- initial RHS in fragment order: ct0-3 = dsq*X, ct4-7 = dinv*X ----------
__global__ __launch_bounds__(256) void k_prep(const float* __restrict__ X,
    const float* __restrict__ dinv, const float* __restrict__ dsq,
    unsigned short* __restrict__ Bt)
{
  const int b = blockIdx.y, n0 = blockIdx.x * 64, tid = threadIdx.x;
  __shared__ unsigned short tg[64][68], ts[64][68];   // 68*2=136=17*8 aligned
  #pragma unroll
  for (int i = 0; i < 4; ++i){
    int idx = i * 256 + tid, n = idx >> 4, c4 = (idx & 15) * 4;
    size_t rb = (size_t)b * NN + n0 + n;
    float4 x = *(const float4*)(X + rb * 64 + c4);
    float di = dinv[b * NN + n0 + n], dv = dsq[b * NN + n0 + n];
    tg[c4 + 0][n] = f2bf(dv * x.x); tg[c4 + 1][n] = f2bf(dv * x.y);
    tg[c4 + 2][n] = f2bf(dv * x.z); tg[c4 + 3][n] = f2bf(dv * x.w);
    ts[c4 + 0][n] = f2bf(di * x.x); ts[c4 + 1][n] = f2bf(di * x.y);
    ts[c4 + 2][n] = f2bf(di * x.z); ts[c4 + 3][n] = f2bf(di * x.w);
  }
  __syncthreads();
  const int t = n0 >> 6;
  #pragma unroll
  for (int it = 0; it < 8; ++it){
    int idx = it * 256 + tid;
    int half = idx & 1, l = (idx >> 1) & 63, kk = (idx >> 7) & 1, ct = (idx >> 8) & 7;
    int cl = ((ct & 3) << 4) + (l & 15);
    int nl = kk * 32 + ((l >> 4) << 3) + half * 4;
    ushort4 v = (ct < 4) ? *(const ushort4*)&tg[cl][nl] : *(const ushort4*)&ts[cl][nl];
    *(ushort4*)(Bt + ((((size_t)b * 8 + ct) * 64 + t) * 2 + kk) * 512 + (l << 3) + half * 4) = v;
  }
}

// ---------------- fused GEMM + epilogue: NO LDS, NO BARRIERS, fragment loads ----------
template<int NC>
__global__ __launch_bounds__(256, 4) void k_gemm_fused(
    const unsigned short* __restrict__ At,
    const unsigned short* __restrict__ BtR, int ct0,
    const float* __restrict__ sprev, float* __restrict__ P, float* __restrict__ snap,
    const float* __restrict__ dinv, int writeVtS,
    const float* __restrict__ gprev, float* __restrict__ gout,
    const float* __restrict__ dsq, int writeVtG,
    unsigned short* __restrict__ BtW)
{
  constexpr int NF = NC / 64;
  const int bid = blockIdx.x;
  const int b = bid & 7, mt = bid >> 3, m0 = mt * 32;
  const int tid = threadIdx.x;
  const int w = tid >> 6, l = tid & 63;
  const int r0 = l & 15, hq = l >> 4;

  const unsigned short* Ab = At + (size_t)bid * 131072 + (l << 3);
  const unsigned short* Bb[NF];
  #pragma unroll
  for (int ni = 0; ni < NF; ++ni)
    Bb[ni] = BtR + (((size_t)b * 8 + ct0 + w * NF + ni) * 64) * 1024 + (l << 3);

  bf16x8 a0[2][2], a1[2][2];     // [kk][mi]
  bf16x8 b0[NF][2], b1[NF][2];   // [ni][kk]
  f32x4 acc[2][NF];
  #pragma unroll
  for (int mi = 0; mi < 2; ++mi)
    #pragma unroll
    for (int ni = 0; ni < NF; ++ni)
      #pragma unroll
      for (int j = 0; j < 4; ++j) acc[mi][ni][j] = 0.f;

  auto LDA = [&](bf16x8 (&pa)[2][2], int t){
    #pragma unroll
    for (int kk = 0; kk < 2; ++kk)
      #pragma unroll
      for (int mi = 0; mi < 2; ++mi)
        pa[kk][mi] = *(const bf16x8*)(Ab + (size_t)t * 2048 + (kk * 2 + mi) * 512);
  };
  auto LDB = [&](bf16x8 (&pb)[NF][2], int t){
    #pragma unroll
    for (int ni = 0; ni < NF; ++ni)
      #pragma unroll
      for (int kk = 0; kk < 2; ++kk)
        pb[ni][kk] = *(const bf16x8*)(Bb[ni] + (size_t)t * 1024 + kk * 512);
  };
  auto FMA = [&](bf16x8 (&pa)[2][2], bf16x8 (&pb)[NF][2]){
    #pragma unroll
    for (int kk = 0; kk < 2; ++kk)
      #pragma unroll
      for (int mi = 0; mi < 2; ++mi)
        #pragma unroll
        for (int ni = 0; ni < NF; ++ni)
          acc[mi][ni] = __builtin_amdgcn_mfma_f32_16x16x32_bf16(
              pa[kk][mi], pb[ni][kk], acc[mi][ni], 0, 0, 0);
  };

  LDA(a0, 0); LDB(b0, 0);
  #pragma unroll 1
  for (int t = 0; t < 64; t += 2){
    LDA(a1, t + 1); LDB(b1, t + 1);
    FMA(a0, b0);
    if (t + 2 < 64){ LDA(a0, t + 2); LDB(b0, t + 2); }
    FMA(a1, b1);
  }

  // ---- fused epilogue: C/D layout col = lane&15 (r0), row = hq*4 + j ----
  const bool isScat = (NC == 64) || (w >= 2);
  if (isScat){
    const int wS = (NC == 64) ? w : (w - 2);
    #pragma unroll
    for (int mi = 0; mi < 2; ++mi){
      const int rb = m0 + mi * 16 + hq * 4;
      const size_t rowb = (size_t)b * NN + rb;
      float4 dv4 = *(const float4*)(dinv + (size_t)b * NN + rb);
      #pragma unroll
      for (int ni = 0; ni < NF; ++ni){
        const int cs = wS * 16 * NF + ni * 16 + r0;   // local scat col 0..63
        float pn[4];
        #pragma unroll
        for (int j = 0; j < 4; ++j){
          float pv = sprev[(rowb + j) * 64 + cs];
          pn[j] = 0.5f * (pv + acc[mi][ni][j]);
          P[(rowb + j) * 64 + cs] = pn[j];
        }
        if (snap){
          #pragma unroll
          for (int j = 0; j < 4; ++j) snap[(rowb + j) * 64 + cs] = pn[j];
        }
        if (writeVtS){
          const int ct = 4 + wS * NF + ni;
          const int tp = rb >> 6, kkp = (rb >> 5) & 1;
          const int lp = r0 + 16 * ((rb >> 3) & 3), hf = (rb >> 2) & 1;
          ushort4 vv = make_ushort4(f2bf(dv4.x * pn[0]), f2bf(dv4.y * pn[1]),
                                    f2bf(dv4.z * pn[2]), f2bf(dv4.w * pn[3]));
          *(ushort4*)(BtW + ((((size_t)b * 8 + ct) * 64 + tp) * 2 + kkp) * 512
                          + (lp << 3) + hf * 4) = vv;
        }
      }
    }
  }
  if constexpr (NC == 128){
    if (!isScat){                                     // gcn waves 0,1
      #pragma unroll
      for (int mi = 0; mi < 2; ++mi){
        const int rb = m0 + mi * 16 + hq * 4;
        const size_t rowb = (size_t)b * NN + rb;
        float4 dq4 = *(const float4*)(dsq + (size_t)b * NN + rb);
        #pragma unroll
        for (int ni = 0; ni < NF; ++ni){
          const int cg = w * 16 * NF + ni * 16 + r0;  // gcn col 0..63
          float hn[4];
          const float dq[4] = {dq4.x, dq4.y, dq4.z, dq4.w};
          #pragma unroll
          for (int j = 0; j < 4; ++j){
            float hv = gprev[(rowb + j) * 64 + cg];
            hn[j] = (acc[mi][ni][j] + dq[j] * hv) * dq[j];
            gout[(rowb + j) * 64 + cg] = hn[j];
          }
          if (writeVtG){
            const int ct = w * NF + ni;
            const int tp = rb >> 6, kkp = (rb >> 5) & 1;
            const int lp = r0 + 16 * ((rb >> 3) & 3), hf = (rb >> 2) & 1;
            ushort4 vv = make_ushort4(f2bf(dq[0] * hn[0]), f2bf(dq[1] * hn[1]),
                                      f2bf(dq[2] * hn[2]), f2bf(dq[3] * hn[3]));
            *(ushort4*)(BtW + ((((size_t)b * 8 + ct) * 64 + tp) * 2 + kkp) * 512
                            + (lp << 3) + hf * 4) = vv;
          }
        }
      }
    }
  }
}

// ---------------- attention over 6 branches + 2-layer MLP ----------------
__global__ __launch_bounds__(256) void k_attn(
    const float* __restrict__ X,  const float* __restrict__ hA, const float* __restrict__ hA2,
    const float* __restrict__ U1, const float* __restrict__ U2, const float* __restrict__ U4,
    const float* __restrict__ U8, const float* __restrict__ W1, const float* __restrict__ b1,
    const float* __restrict__ W2, const float* __restrict__ b2, const float* __restrict__ av,
    const int* __restrict__ momp, float* __restrict__ out)
{
  __shared__ float W1s[64][65], W2s[64][65];
  __shared__ float a1s[64], a2s[64], b1s[64], b2s[64];
  __shared__ float hp[4][64], o1[4][64];
  const int tid = threadIdx.x;
  for (int e = tid; e < 4096; e += 256){
    W1s[e >> 6][e & 63] = W1[e];
    W2s[e >> 6][e & 63] = W2[e];
  }
  if (tid < 64){ a1s[tid] = av[tid]; a2s[tid] = av[64 + tid]; b1s[tid] = b1[tid]; b2s[tid] = b2[tid]; }
  __syncthreads();
  const int w = tid >> 6, l = tid & 63;
  size_t row = (size_t)blockIdx.x * 4 + w;
  size_t off = row * 64 + l;
  float x  = X[off];
  float u1 = U1[off], u2 = U2[off], u4 = U4[off], u8 = U8[off];
  float br[6];
  br[0] = leaky01(hA[off]);
  br[1] = leaky01(hA2[off]);
  float d1 = fabsf(x - u1), d2 = fabsf(u1 - u2), d3 = fabsf(u2 - u4), d4 = fabsf(u4 - u8);
  int mom = *momp;
  if (mom == 1){ br[2] = d1; br[3] = d2; br[4] = d3; br[5] = d4; }
  else {
    float m = (float)mom;
    br[2] = powf(d1, m); br[3] = powf(d2, m); br[4] = powf(d3, m); br[5] = powf(d4, m);
  }
  float v = fmaxf(x, 0.f) * a1s[l];
  for (int o = 32; o; o >>= 1) v += __shfl_xor(v, o);
  float base = v;
  float e[6];
  #pragma unroll
  for (int k = 0; k < 6; ++k){
    float t = fmaxf(br[k], 0.f) * a2s[l];
    for (int o = 32; o; o >>= 1) t += __shfl_xor(t, o);
    e[k] = base + t;
  }
  float mx = e[0];
  #pragma unroll
  for (int k = 1; k < 6; ++k) mx = fmaxf(mx, e[k]);
  float s = 0.f, att[6];
  #pragma unroll
  for (int k = 0; k < 6; ++k){ att[k] = expf(e[k] - mx); s += att[k]; }
  float inv = 1.0f / (6.0f * s);
  float hpv = 0.f;
  #pragma unroll
  for (int k = 0; k < 6; ++k) hpv += att[k] * br[k];
  hpv *= inv;
  hp[w][l] = hpv;
  __syncthreads();
  float acc = b1s[l];
  #pragma unroll 8
  for (int c = 0; c < 64; ++c) acc += hp[w][c] * W1s[l][c];
  o1[w][l] = leaky01(acc);
  __syncthreads();
  float acc2 = b2s[l];
  #pragma unroll 8
  for (int c = 0; c < 64; ++c) acc2 += o1[w][c] * W2s[l][c];
  out[off] = leaky01(acc2);
}

// ---------------- workspace layout ----------------
static constexpr size_t OFF_ADJB = 0;                                   // bf16 frag-order A
static constexpr size_t OFF_VTA  = OFF_ADJB + (size_t)BB * NN * NN * 2; // bf16 frag-order B
static constexpr size_t OFF_VTB  = OFF_VTA  + (size_t)BB * 128 * NN * 2;
static constexpr size_t OFF_HA   = OFF_VTB  + (size_t)BB * 128 * NN * 2;
static constexpr size_t OFF_HA2  = OFF_HA   + (size_t)BB * NN * 64 * 4;
static constexpr size_t OFF_P    = OFF_HA2  + (size_t)BB * NN * 64 * 4;
static constexpr size_t OFF_U1   = OFF_P    + (size_t)BB * NN * 64 * 4;
static constexpr size_t OFF_U2   = OFF_U1   + (size_t)BB * NN * 64 * 4;
static constexpr size_t OFF_U4   = OFF_U2   + (size_t)BB * NN * 64 * 4;
static constexpr size_t OFF_U8   = OFF_U4   + (size_t)BB * NN * 64 * 4;
static constexpr size_t OFF_DINV = OFF_U8   + (size_t)BB * NN * 64 * 4;
static constexpr size_t OFF_DS   = OFF_DINV + (size_t)BB * NN * 4;
static constexpr size_t WS_NEED  = OFF_DS   + (size_t)BB * NN * 4;

extern "C" void kernel_launch(void* const* d_in, const int* in_sizes, int n_in,
                              void* d_out, int out_size, void* d_ws, size_t ws_size,
                              hipStream_t stream)
{
  const float* X   = (const float*)d_in[0];
  const float* adj = (const float*)d_in[1];
  const float* W1  = (const float*)d_in[2];
  const float* b1  = (const float*)d_in[3];
  const float* W2  = (const float*)d_in[4];
  const float* b2  = (const float*)d_in[5];
  const float* av  = (const float*)d_in[6];
  const int*  momp = (const int*)d_in[7];
  float* out = (float*)d_out;

  if (ws_size < WS_NEED){
    fprintf(stderr, "kernel_launch: workspace too small: %zu < %zu\n", ws_size, WS_NEED);
    return;
  }
  char* w = (char*)d_ws;
  unsigned short* At  = (unsigned short*)(w + OFF_ADJB);
  unsigned short* vtA = (unsigned short*)(w + OFF_VTA);
  unsigned short* vtB = (unsigned short*)(w + OFF_VTB);
  float* hA   = (float*)(w + OFF_HA);
  float* hA2  = (float*)(w + OFF_HA2);
  float* P    = (float*)(w + OFF_P);
  float* U1   = (float*)(w + OFF_U1);
  float* U2   = (float*)(w + OFF_U2);
  float* U4   = (float*)(w + OFF_U4);
  float* U8   = (float*)(w + OFF_U8);
  float* dinv = (float*)(w + OFF_DINV);
  float* dsq  = (float*)(w + OFF_DS);

  k_convert<<<1024, 256, 0, stream>>>(adj, At, dinv, dsq);
  dim3 tg64(NN / 64, BB);
  k_prep<<<tg64, 256, 0, stream>>>(X, dinv, dsq, vtA);

  // pass 1: dual RHS (gcn: dsq*X -> hA, scat: dinv*X -> P,U1); writes vtB (both halves)
  k_gemm_fused<128><<<1024, 256, 0, stream>>>(At, vtA, 0,
      X, P, U1, dinv, 1, X, hA, dsq, 1, vtB);
  // pass 2: dual RHS (gcn -> hA2, scat -> P,U2); writes vtA (scat half)
  k_gemm_fused<128><<<1024, 256, 0, stream>>>(At, vtB, 0,
      P, P, U2, dinv, 1, hA, hA2, dsq, 0, vtA);
  // passes 3..8: scattering only, alternate vtA/vtB
  unsigned short* vr = vtA;
  unsigned short* vw = vtB;
  for (int k = 3; k <= 8; ++k){
    float* snap = (k == 4) ? U4 : nullptr;
    float* pdst = (k == 8) ? U8 : P;
    k_gemm_fused<64><<<1024, 256, 0, stream>>>(At, vr, 4,
        P, pdst, snap, dinv, (k < 8) ? 1 : 0, nullptr, nullptr, nullptr, 0, vw);
    unsigned short* t = vr; vr = vw; vw = t;
  }

  k_attn<<<BB * NN / 4, 256, 0, stream>>>(X, hA, hA2, U1, U2, U4, U8,
                                          W1, b1, W2, b2, av, momp, out);
}

// Round 10
// 784.880 us; speedup vs baseline: 1.2720x; 1.2720x over previous
//
#include <hip/hip_runtime.h>
#include <hip/hip_bf16.h>
#include <cstdio>
#include <cstdint>

#define BB 8
#define NN 4096
#define FF 64

typedef __attribute__((ext_vector_type(8))) short bf16x8;
typedef __attribute__((ext_vector_type(4))) float f32x4;

__device__ __forceinline__ unsigned short f2bf(float f){
  unsigned int u = __float_as_uint(f);
  u += 0x7FFFu + ((u >> 16) & 1u);           // round-to-nearest-even
  return (unsigned short)(u >> 16);
}

__device__ __forceinline__ float leaky01(float x){ return x > 0.f ? x : 0.01f * x; }

// ================= layouts =================
// A (R4-proven staging image, XOR baked in source cols):
//   At[bid][t][(r*8+g)*8+j] = bf16(adj[b][m0+r][t*64 + ((g^(r&7))<<3) + j]), bid=b+8*mt
// B (R9-proven fragment order):
//   Bt[b][ct(8)][t(64)][kk(2)][l(64)][j(8)]
//     element = scale * H[row = t*64 + kk*32 + (l>>4)*8 + j][col = ct*16 + (l&15)]
//     ct 0..3 = gcn half (cols 0..63), ct 4..7 = scat half

// ---------------- pass 0: fp32 adj -> A staging image + row sums (R4 verbatim) ----------
__global__ __launch_bounds__(256) void k_convert(const float* __restrict__ adj,
    unsigned short* __restrict__ At, float* __restrict__ dinv, float* __restrict__ dsq)
{
  const int bid = blockIdx.x;              // 1024 blocks; b = bid&7 (XCD-aligned)
  const int b = bid & 7, mt = bid >> 3, m0 = mt * 32;
  const int tid = threadIdx.x;
  const int r = tid >> 3, g = tid & 7;
  const float* src = adj + ((size_t)b * NN + m0 + r) * NN + ((g ^ (r & 7)) << 3);
  unsigned short* dst = At + (size_t)bid * 64 * 2048 + (tid << 3);
  float s = 0.f;
  for (int t = 0; t < 64; ++t){
    const float* p = src + t * 64;
    float4 a = *(const float4*)p;
    float4 c = *(const float4*)(p + 4);
    s += ((a.x + a.y) + (a.z + a.w)) + ((c.x + c.y) + (c.z + c.w));
    bf16x8 v;
    v[0] = (short)f2bf(a.x); v[1] = (short)f2bf(a.y); v[2] = (short)f2bf(a.z); v[3] = (short)f2bf(a.w);
    v[4] = (short)f2bf(c.x); v[5] = (short)f2bf(c.y); v[6] = (short)f2bf(c.z); v[7] = (short)f2bf(c.w);
    *(bf16x8*)(dst + (size_t)t * 2048) = v;
  }
  s += __shfl_xor(s, 1); s += __shfl_xor(s, 2); s += __shfl_xor(s, 4);
  if (g == 0){
    dinv[(size_t)b * NN + m0 + r] = 1.0f / s;              // scattering: rowsum of adj
    dsq [(size_t)b * NN + m0 + r] = 1.0f / sqrtf(s + 1.0f);// gcn: rowsum(adj+I)^-1/2
  }
}

// ---------------- initial RHS in fragment order: ct0-3 = dsq*X, ct4-7 = dinv*X (R9) ----
__global__ __launch_bounds__(256) void k_prep(const float* __restrict__ X,
    const float* __restrict__ dinv, const float* __restrict__ dsq,
    unsigned short* __restrict__ Bt)
{
  const int b = blockIdx.y, n0 = blockIdx.x * 64, tid = threadIdx.x;
  __shared__ unsigned short tg[64][68], ts[64][68];
  #pragma unroll
  for (int i = 0; i < 4; ++i){
    int idx = i * 256 + tid, n = idx >> 4, c4 = (idx & 15) * 4;
    size_t rb = (size_t)b * NN + n0 + n;
    float4 x = *(const float4*)(X + rb * 64 + c4);
    float di = dinv[b * NN + n0 + n], dv = dsq[b * NN + n0 + n];
    tg[c4 + 0][n] = f2bf(dv * x.x); tg[c4 + 1][n] = f2bf(dv * x.y);
    tg[c4 + 2][n] = f2bf(dv * x.z); tg[c4 + 3][n] = f2bf(dv * x.w);
    ts[c4 + 0][n] = f2bf(di * x.x); ts[c4 + 1][n] = f2bf(di * x.y);
    ts[c4 + 2][n] = f2bf(di * x.z); ts[c4 + 3][n] = f2bf(di * x.w);
  }
  __syncthreads();
  const int t = n0 >> 6;
  #pragma unroll
  for (int it = 0; it < 8; ++it){
    int idx = it * 256 + tid;
    int half = idx & 1, l = (idx >> 1) & 63, kk = (idx >> 7) & 1, ct = (idx >> 8) & 7;
    int cl = ((ct & 3) << 4) + (l & 15);
    int nl = kk * 32 + ((l >> 4) << 3) + half * 4;
    ushort4 v = (ct < 4) ? *(const ushort4*)&tg[cl][nl] : *(const ushort4*)&ts[cl][nl];
    *(ushort4*)(Bt + ((((size_t)b * 8 + ct) * 64 + t) * 2 + kk) * 512 + (l << 3) + half * 4) = v;
  }
}

// -------- fused GEMM + epilogue: A via 4-deep LDS (1 barrier/k-tile), B reg-direct -----
template<int NC>
__global__ __launch_bounds__(256, 4) void k_gemm_fused(
    const unsigned short* __restrict__ At,
    const unsigned short* __restrict__ BtR, int ct0,
    const float* __restrict__ sprev, float* __restrict__ P, float* __restrict__ snap,
    const float* __restrict__ dinv, int writeVtS,
    const float* __restrict__ gprev, float* __restrict__ gout,
    const float* __restrict__ dsq, int writeVtG,
    unsigned short* __restrict__ BtW)
{
  constexpr int NF = NC / 64;
  __shared__ __align__(16) unsigned short As[4][32 * 64];   // 16 KB, 4-deep
  const int bid = blockIdx.x;
  const int b = bid & 7, mt = bid >> 3, m0 = mt * 32;
  const int tid = threadIdx.x;
  const int w = tid >> 6, l = tid & 63;
  const int r0 = l & 15, hq = l >> 4, sw = r0 & 7;
  const unsigned short* Atile = At + (size_t)bid * 131072;
  const unsigned short* Bb[NF];
  #pragma unroll
  for (int ni = 0; ni < NF; ++ni)
    Bb[ni] = BtR + (((size_t)b * 8 + ct0 + w * NF + ni) * 64) * 1024 + (l << 3);

  auto stageA = [&](int buf, int t){
    const unsigned short* gp = Atile + (size_t)t * 2048 + (tid << 3);  // contiguous
    __builtin_amdgcn_global_load_lds((const __attribute__((address_space(1))) void*)gp,
        (__attribute__((address_space(3))) void*)(&As[buf][tid << 3]), 16, 0, 0);
  };
  auto LDB = [&](bf16x8 (&pb)[NF][2], int t){
    #pragma unroll
    for (int ni = 0; ni < NF; ++ni)
      #pragma unroll
      for (int kk = 0; kk < 2; ++kk)
        pb[ni][kk] = *(const bf16x8*)(Bb[ni] + (size_t)t * 1024 + kk * 512);
  };

  bf16x8 b0[NF][2], b1[NF][2];
  f32x4 acc[2][NF];
  #pragma unroll
  for (int mi = 0; mi < 2; ++mi)
    #pragma unroll
    for (int ni = 0; ni < NF; ++ni)
      #pragma unroll
      for (int j = 0; j < 4; ++j) acc[mi][ni][j] = 0.f;

  stageA(0, 0); stageA(1, 1); stageA(2, 2);
  LDB(b0, 0);

  // one barrier per k-tile; A has 3-tile slack; B self-paced per wave
  #define SUBSTEP(T, BCUR, BNXT)                                                  \
    do {                                                                          \
      const int _t = (T);                                                         \
      __builtin_amdgcn_s_barrier();                                               \
      asm volatile("" ::: "memory");                                              \
      const bool _st = (_t + 3 < 64);                                             \
      if (_st) stageA((_t + 3) & 3, _t + 3);                                      \
      if (_t + 1 < 64) LDB(BNXT, _t + 1);                                         \
      if (_t >= 61){ asm volatile("s_waitcnt vmcnt(0)" ::: "memory"); }           \
      else if constexpr (NC == 128){ asm volatile("s_waitcnt vmcnt(5)" ::: "memory"); } \
      else { asm volatile("s_waitcnt vmcnt(3)" ::: "memory"); }                   \
      asm volatile("" ::: "memory");                                              \
      _Pragma("unroll")                                                           \
      for (int kk = 0; kk < 2; ++kk){                                             \
        const int g8 = ((kk * 4 + hq) ^ sw) << 3;                                 \
        bf16x8 af0 = *(const bf16x8*)&As[_t & 3][(r0) * 64 + g8];                 \
        bf16x8 af1 = *(const bf16x8*)&As[_t & 3][(16 + r0) * 64 + g8];            \
        _Pragma("unroll")                                                         \
        for (int ni = 0; ni < NF; ++ni){                                          \
          acc[0][ni] = __builtin_amdgcn_mfma_f32_16x16x32_bf16(af0, BCUR[ni][kk], acc[0][ni], 0, 0, 0); \
          acc[1][ni] = __builtin_amdgcn_mfma_f32_16x16x32_bf16(af1, BCUR[ni][kk], acc[1][ni], 0, 0, 0); \
        }                                                                         \
      }                                                                           \
      asm volatile("" ::: "memory");                                              \
    } while (0)

  #pragma unroll 1
  for (int t = 0; t < 64; t += 2){
    SUBSTEP(t,     b0, b1);
    SUBSTEP(t + 1, b1, b0);
  }
  #undef SUBSTEP

  // ---- fused epilogue: C/D layout col = lane&15 (r0), row = hq*4 + j ----
  const bool isScat = (NC == 64) || (w >= 2);
  if (isScat){
    const int wS = (NC == 64) ? w : (w - 2);
    #pragma unroll
    for (int mi = 0; mi < 2; ++mi){
      const int rb = m0 + mi * 16 + hq * 4;
      const size_t rowb = (size_t)b * NN + rb;
      float4 dv4 = *(const float4*)(dinv + (size_t)b * NN + rb);
      #pragma unroll
      for (int ni = 0; ni < NF; ++ni){
        const int cs = wS * 16 * NF + ni * 16 + r0;   // local scat col 0..63
        float pn[4];
        #pragma unroll
        for (int j = 0; j < 4; ++j){
          float pv = sprev[(rowb + j) * 64 + cs];
          pn[j] = 0.5f * (pv + acc[mi][ni][j]);
          P[(rowb + j) * 64 + cs] = pn[j];
        }
        if (snap){
          #pragma unroll
          for (int j = 0; j < 4; ++j) snap[(rowb + j) * 64 + cs] = pn[j];
        }
        if (writeVtS){
          const int ct = 4 + wS * NF + ni;
          const int tp = rb >> 6, kkp = (rb >> 5) & 1;
          const int lp = r0 + 16 * ((rb >> 3) & 3), hf = (rb >> 2) & 1;
          ushort4 vv = make_ushort4(f2bf(dv4.x * pn[0]), f2bf(dv4.y * pn[1]),
                                    f2bf(dv4.z * pn[2]), f2bf(dv4.w * pn[3]));
          *(ushort4*)(BtW + ((((size_t)b * 8 + ct) * 64 + tp) * 2 + kkp) * 512
                          + (lp << 3) + hf * 4) = vv;
        }
      }
    }
  }
  if constexpr (NC == 128){
    if (!isScat){                                     // gcn waves 0,1
      #pragma unroll
      for (int mi = 0; mi < 2; ++mi){
        const int rb = m0 + mi * 16 + hq * 4;
        const size_t rowb = (size_t)b * NN + rb;
        float4 dq4 = *(const float4*)(dsq + (size_t)b * NN + rb);
        #pragma unroll
        for (int ni = 0; ni < NF; ++ni){
          const int cg = w * 16 * NF + ni * 16 + r0;  // gcn col 0..63
          float hn[4];
          const float dq[4] = {dq4.x, dq4.y, dq4.z, dq4.w};
          #pragma unroll
          for (int j = 0; j < 4; ++j){
            float hv = gprev[(rowb + j) * 64 + cg];
            hn[j] = (acc[mi][ni][j] + dq[j] * hv) * dq[j];
            gout[(rowb + j) * 64 + cg] = hn[j];
          }
          if (writeVtG){
            const int ct = w * NF + ni;
            const int tp = rb >> 6, kkp = (rb >> 5) & 1;
            const int lp = r0 + 16 * ((rb >> 3) & 3), hf = (rb >> 2) & 1;
            ushort4 vv = make_ushort4(f2bf(dq[0] * hn[0]), f2bf(dq[1] * hn[1]),
                                      f2bf(dq[2] * hn[2]), f2bf(dq[3] * hn[3]));
            *(ushort4*)(BtW + ((((size_t)b * 8 + ct) * 64 + tp) * 2 + kkp) * 512
                            + (lp << 3) + hf * 4) = vv;
          }
        }
      }
    }
  }
}

// ---------------- attention over 6 branches + 2-layer MLP ----------------
__global__ __launch_bounds__(256) void k_attn(
    const float* __restrict__ X,  const float* __restrict__ hA, const float* __restrict__ hA2,
    const float* __restrict__ U1, const float* __restrict__ U2, const float* __restrict__ U4,
    const float* __restrict__ U8, const float* __restrict__ W1, const float* __restrict__ b1,
    const float* __restrict__ W2, const float* __restrict__ b2, const float* __restrict__ av,
    const int* __restrict__ momp, float* __restrict__ out)
{
  __shared__ float W1s[64][65], W2s[64][65];
  __shared__ float a1s[64], a2s[64], b1s[64], b2s[64];
  __shared__ float hp[4][64], o1[4][64];
  const int tid = threadIdx.x;
  for (int e = tid; e < 4096; e += 256){
    W1s[e >> 6][e & 63] = W1[e];
    W2s[e >> 6][e & 63] = W2[e];
  }
  if (tid < 64){ a1s[tid] = av[tid]; a2s[tid] = av[64 + tid]; b1s[tid] = b1[tid]; b2s[tid] = b2[tid]; }
  __syncthreads();
  const int w = tid >> 6, l = tid & 63;
  size_t row = (size_t)blockIdx.x * 4 + w;
  size_t off = row * 64 + l;
  float x  = X[off];
  float u1 = U1[off], u2 = U2[off], u4 = U4[off], u8 = U8[off];
  float br[6];
  br[0] = leaky01(hA[off]);
  br[1] = leaky01(hA2[off]);
  float d1 = fabsf(x - u1), d2 = fabsf(u1 - u2), d3 = fabsf(u2 - u4), d4 = fabsf(u4 - u8);
  int mom = *momp;
  if (mom == 1){ br[2] = d1; br[3] = d2; br[4] = d3; br[5] = d4; }
  else {
    float m = (float)mom;
    br[2] = powf(d1, m); br[3] = powf(d2, m); br[4] = powf(d3, m); br[5] = powf(d4, m);
  }
  float v = fmaxf(x, 0.f) * a1s[l];
  for (int o = 32; o; o >>= 1) v += __shfl_xor(v, o);
  float base = v;
  float e[6];
  #pragma unroll
  for (int k = 0; k < 6; ++k){
    float t = fmaxf(br[k], 0.f) * a2s[l];
    for (int o = 32; o; o >>= 1) t += __shfl_xor(t, o);
    e[k] = base + t;
  }
  float mx = e[0];
  #pragma unroll
  for (int k = 1; k < 6; ++k) mx = fmaxf(mx, e[k]);
  float s = 0.f, att[6];
  #pragma unroll
  for (int k = 0; k < 6; ++k){ att[k] = expf(e[k] - mx); s += att[k]; }
  float inv = 1.0f / (6.0f * s);
  float hpv = 0.f;
  #pragma unroll
  for (int k = 0; k < 6; ++k) hpv += att[k] * br[k];
  hpv *= inv;
  hp[w][l] = hpv;
  __syncthreads();
  float acc = b1s[l];
  #pragma unroll 8
  for (int c = 0; c < 64; ++c) acc += hp[w][c] * W1s[l][c];
  o1[w][l] = leaky01(acc);
  __syncthreads();
  float acc2 = b2s[l];
  #pragma unroll 8
  for (int c = 0; c < 64; ++c) acc2 += o1[w][c] * W2s[l][c];
  out[off] = leaky01(acc2);
}

// ---------------- workspace layout ----------------
static constexpr size_t OFF_ADJB = 0;                                   // bf16 A staging image
static constexpr size_t OFF_VTA  = OFF_ADJB + (size_t)BB * NN * NN * 2; // bf16 frag-order B
static constexpr size_t OFF_VTB  = OFF_VTA  + (size_t)BB * 128 * NN * 2;
static constexpr size_t OFF_HA   = OFF_VTB  + (size_t)BB * 128 * NN * 2;
static constexpr size_t OFF_HA2  = OFF_HA   + (size_t)BB * NN * 64 * 4;
static constexpr size_t OFF_P    = OFF_HA2  + (size_t)BB * NN * 64 * 4;
static constexpr size_t OFF_U1   = OFF_P    + (size_t)BB * NN * 64 * 4;
static constexpr size_t OFF_U2   = OFF_U1   + (size_t)BB * NN * 64 * 4;
static constexpr size_t OFF_U4   = OFF_U2   + (size_t)BB * NN * 64 * 4;
static constexpr size_t OFF_U8   = OFF_U4   + (size_t)BB * NN * 64 * 4;
static constexpr size_t OFF_DINV = OFF_U8   + (size_t)BB * NN * 64 * 4;
static constexpr size_t OFF_DS   = OFF_DINV + (size_t)BB * NN * 4;
static constexpr size_t WS_NEED  = OFF_DS   + (size_t)BB * NN * 4;

extern "C" void kernel_launch(void* const* d_in, const int* in_sizes, int n_in,
                              void* d_out, int out_size, void* d_ws, size_t ws_size,
                              hipStream_t stream)
{
  const float* X   = (const float*)d_in[0];
  const float* adj = (const float*)d_in[1];
  const float* W1  = (const float*)d_in[2];
  const float* b1  = (const float*)d_in[3];
  const float* W2  = (const float*)d_in[4];
  const float* b2  = (const float*)d_in[5];
  const float* av  = (const float*)d_in[6];
  const int*  momp = (const int*)d_in[7];
  float* out = (float*)d_out;

  if (ws_size < WS_NEED){
    fprintf(stderr, "kernel_launch: workspace too small: %zu < %zu\n", ws_size, WS_NEED);
    return;
  }
  char* w = (char*)d_ws;
  unsigned short* At  = (unsigned short*)(w + OFF_ADJB);
  unsigned short* vtA = (unsigned short*)(w + OFF_VTA);
  unsigned short* vtB = (unsigned short*)(w + OFF_VTB);
  float* hA   = (float*)(w + OFF_HA);
  float* hA2  = (float*)(w + OFF_HA2);
  float* P    = (float*)(w + OFF_P);
  float* U1   = (float*)(w + OFF_U1);
  float* U2   = (float*)(w + OFF_U2);
  float* U4   = (float*)(w + OFF_U4);
  float* U8   = (float*)(w + OFF_U8);
  float* dinv = (float*)(w + OFF_DINV);
  float* dsq  = (float*)(w + OFF_DS);

  k_convert<<<1024, 256, 0, stream>>>(adj, At, dinv, dsq);
  dim3 tg64(NN / 64, BB);
  k_prep<<<tg64, 256, 0, stream>>>(X, dinv, dsq, vtA);

  // pass 1: dual RHS (gcn: dsq*X -> hA, scat: dinv*X -> P,U1); writes vtB (both halves)
  k_gemm_fused<128><<<1024, 256, 0, stream>>>(At, vtA, 0,
      X, P, U1, dinv, 1, X, hA, dsq, 1, vtB);
  // pass 2: dual RHS (gcn -> hA2, scat -> P,U2); writes vtA (scat half)
  k_gemm_fused<128><<<1024, 256, 0, stream>>>(At, vtB, 0,
      P, P, U2, dinv, 1, hA, hA2, dsq, 0, vtA);
  // passes 3..8: scattering only, alternate vtA/vtB
  unsigned short* vr = vtA;
  unsigned short* vw = vtB;
  for (int k = 3; k <= 8; ++k){
    float* snap = (k == 4) ? U4 : nullptr;
    float* pdst = (k == 8) ? U8 : P;
    k_gemm_fused<64><<<1024, 256, 0, stream>>>(At, vr, 4,
        P, pdst, snap, dinv, (k < 8) ? 1 : 0, nullptr, nullptr, nullptr, 0, vw);
    unsigned short* t = vr; vr = vw; vw = t;
  }

  k_attn<<<BB * NN / 4, 256, 0, stream>>>(X, hA, hA2, U1, U2, U4, U8,
                                          W1, b1, W2, b2, av, momp, out);
}

// Round 11
// 782.831 us; speedup vs baseline: 1.2754x; 1.0026x over previous
//
#include <hip/hip_runtime.h>
#include <hip/hip_bf16.h>
#include <cstdio>
#include <cstdint>

#define BB 8
#define NN 4096
#define FF 64

typedef __attribute__((ext_vector_type(8))) short bf16x8;
typedef __attribute__((ext_vector_type(4))) float f32x4;

__device__ __forceinline__ unsigned short f2bf(float f){
  unsigned int u = __float_as_uint(f);
  u += 0x7FFFu + ((u >> 16) & 1u);           // round-to-nearest-even
  return (unsigned short)(u >> 16);
}

__device__ __forceinline__ float leaky01(float x){ return x > 0.f ? x : 0.01f * x; }

// ================= layouts =================
// A (R4-proven staging image, XOR baked into source cols):
//   At[bid][t][(r*8+g)*8+j] = bf16(adj[b][m0+r][t*64 + ((g^(r&7))<<3) + j]), bid=b+8*mt
// B (R9-proven fragment order):
//   Bt[b][ct(8)][t(64)][kk(2)][l(64)][j(8)]
//     element = scale * H[row = t*64 + kk*32 + (l>>4)*8 + j][col = ct*16 + (l&15)]
//     ct 0..3 = gcn half (cols 0..63), ct 4..7 = scat half

// ---------------- pass 0: fp32 adj -> A staging image + row sums (R4 verbatim) ----------
__global__ __launch_bounds__(256) void k_convert(const float* __restrict__ adj,
    unsigned short* __restrict__ At, float* __restrict__ dinv, float* __restrict__ dsq)
{
  const int bid = blockIdx.x;              // 1024 blocks; b = bid&7 (XCD-aligned)
  const int b = bid & 7, mt = bid >> 3, m0 = mt * 32;
  const int tid = threadIdx.x;
  const int r = tid >> 3, g = tid & 7;
  const float* src = adj + ((size_t)b * NN + m0 + r) * NN + ((g ^ (r & 7)) << 3);
  unsigned short* dst = At + (size_t)bid * 64 * 2048 + (tid << 3);
  float s = 0.f;
  for (int t = 0; t < 64; ++t){
    const float* p = src + t * 64;
    float4 a = *(const float4*)p;
    float4 c = *(const float4*)(p + 4);
    s += ((a.x + a.y) + (a.z + a.w)) + ((c.x + c.y) + (c.z + c.w));
    bf16x8 v;
    v[0] = (short)f2bf(a.x); v[1] = (short)f2bf(a.y); v[2] = (short)f2bf(a.z); v[3] = (short)f2bf(a.w);
    v[4] = (short)f2bf(c.x); v[5] = (short)f2bf(c.y); v[6] = (short)f2bf(c.z); v[7] = (short)f2bf(c.w);
    *(bf16x8*)(dst + (size_t)t * 2048) = v;
  }
  s += __shfl_xor(s, 1); s += __shfl_xor(s, 2); s += __shfl_xor(s, 4);
  if (g == 0){
    dinv[(size_t)b * NN + m0 + r] = 1.0f / s;              // scattering: rowsum of adj
    dsq [(size_t)b * NN + m0 + r] = 1.0f / sqrtf(s + 1.0f);// gcn: rowsum(adj+I)^-1/2
  }
}

// ---------------- initial RHS in fragment order: ct0-3 = dsq*X, ct4-7 = dinv*X ----------
__global__ __launch_bounds__(256) void k_prep(const float* __restrict__ X,
    const float* __restrict__ dinv, const float* __restrict__ dsq,
    unsigned short* __restrict__ Bt)
{
  const int b = blockIdx.y, n0 = blockIdx.x * 64, tid = threadIdx.x;
  __shared__ unsigned short tg[64][68], ts[64][68];
  #pragma unroll
  for (int i = 0; i < 4; ++i){
    int idx = i * 256 + tid, n = idx >> 4, c4 = (idx & 15) * 4;
    size_t rb = (size_t)b * NN + n0 + n;
    float4 x = *(const float4*)(X + rb * 64 + c4);
    float di = dinv[b * NN + n0 + n], dv = dsq[b * NN + n0 + n];
    tg[c4 + 0][n] = f2bf(dv * x.x); tg[c4 + 1][n] = f2bf(dv * x.y);
    tg[c4 + 2][n] = f2bf(dv * x.z); tg[c4 + 3][n] = f2bf(dv * x.w);
    ts[c4 + 0][n] = f2bf(di * x.x); ts[c4 + 1][n] = f2bf(di * x.y);
    ts[c4 + 2][n] = f2bf(di * x.z); ts[c4 + 3][n] = f2bf(di * x.w);
  }
  __syncthreads();
  const int t = n0 >> 6;
  #pragma unroll
  for (int it = 0; it < 8; ++it){
    int idx = it * 256 + tid;
    int half = idx & 1, l = (idx >> 1) & 63, kk = (idx >> 7) & 1, ct = (idx >> 8) & 7;
    int cl = ((ct & 3) << 4) + (l & 15);
    int nl = kk * 32 + ((l >> 4) << 3) + half * 4;
    ushort4 v = (ct < 4) ? *(const ushort4*)&tg[cl][nl] : *(const ushort4*)&ts[cl][nl];
    *(ushort4*)(Bt + ((((size_t)b * 8 + ct) * 64 + t) * 2 + kk) * 512 + (l << 3) + half * 4) = v;
  }
}

// ---- fused GEMM + epilogue: 5-deep A-LDS pipeline (true slack 3), B reg-direct ----
template<int NC>
__global__ __launch_bounds__(256, 4) void k_gemm_fused(
    const unsigned short* __restrict__ At,
    const unsigned short* __restrict__ BtR, int ct0,
    const float* __restrict__ sprev, float* __restrict__ P, float* __restrict__ snap,
    const float* __restrict__ dinv, int writeVtS,
    const float* __restrict__ gprev, float* __restrict__ gout,
    const float* __restrict__ dsq, int writeVtG,
    unsigned short* __restrict__ BtW)
{
  constexpr int NF = NC / 64;
  constexpr int BAHEAD = (NC == 64) ? 2 : 1;     // B reg prefetch distance
  __shared__ __align__(16) unsigned short As[5][32 * 64];   // 20 KB, 5-deep
  const int bid = blockIdx.x;
  const int b = bid & 7, mt = bid >> 3, m0 = mt * 32;
  const int tid = threadIdx.x;
  const int w = tid >> 6, l = tid & 63;
  const int r0 = l & 15, hq = l >> 4, sw = r0 & 7;
  const unsigned short* Atile = At + (size_t)bid * 131072;
  const unsigned short* Bb[NF];
  #pragma unroll
  for (int ni = 0; ni < NF; ++ni)
    Bb[ni] = BtR + (((size_t)b * 8 + ct0 + w * NF + ni) * 64) * 1024 + (l << 3);

  auto stageA = [&](int buf, int t){
    const unsigned short* gp = Atile + (size_t)t * 2048 + (tid << 3);  // contiguous
    __builtin_amdgcn_global_load_lds((const __attribute__((address_space(1))) void*)gp,
        (__attribute__((address_space(3))) void*)(&As[buf][tid << 3]), 16, 0, 0);
  };
  auto LDB = [&](bf16x8 (&pb)[NF][2], int t){
    #pragma unroll
    for (int ni = 0; ni < NF; ++ni)
      #pragma unroll
      for (int kk = 0; kk < 2; ++kk)
        pb[ni][kk] = *(const bf16x8*)(Bb[ni] + (size_t)t * 1024 + kk * 512);
  };

  f32x4 acc[2][NF];
  #pragma unroll
  for (int mi = 0; mi < 2; ++mi)
    #pragma unroll
    for (int ni = 0; ni < NF; ++ni)
      #pragma unroll
      for (int j = 0; j < 4; ++j) acc[mi][ni][j] = 0.f;

  auto COMPUTE = [&](int ibuf, bf16x8 (&pb)[NF][2]){
    const unsigned short* asb = &As[ibuf][0];
    #pragma unroll
    for (int kk = 0; kk < 2; ++kk){
      const int g8 = ((kk * 4 + hq) ^ sw) << 3;
      bf16x8 af0 = *(const bf16x8*)&asb[(r0) * 64 + g8];
      bf16x8 af1 = *(const bf16x8*)&asb[(16 + r0) * 64 + g8];
      #pragma unroll
      for (int ni = 0; ni < NF; ++ni){
        acc[0][ni] = __builtin_amdgcn_mfma_f32_16x16x32_bf16(af0, pb[ni][kk], acc[0][ni], 0, 0, 0);
        acc[1][ni] = __builtin_amdgcn_mfma_f32_16x16x32_bf16(af1, pb[ni][kk], acc[1][ni], 0, 0, 0);
      }
    }
  };

  bf16x8 b0[NF][2], b1[NF][2], b2[NF][2], b3[NF][2];
  int ibc = 0, ibs = 3;

  // SUB(t): issue LDB(t+BAHEAD), stageA(t+3) -> exact counted wait -> barrier -> compute(t).
  // Fence invariant: the wait retires this wave's stage(t) and LDB(t) before barrier(t),
  // so all waves' tile-t LDS writes are complete before any wave computes tile t.
  #define SUB(T, BCUR, BLD, VM) do {                                            \
    if ((T) + BAHEAD < 64) LDB(BLD, (T) + BAHEAD);                              \
    if ((T) + 3 < 64){ stageA(ibs, (T) + 3); ibs = (ibs == 4) ? 0 : ibs + 1; }  \
    asm volatile("s_waitcnt vmcnt(" #VM ")" ::: "memory");                      \
    __builtin_amdgcn_s_barrier();                                               \
    asm volatile("" ::: "memory");                                              \
    COMPUTE(ibc, BCUR); ibc = (ibc == 4) ? 0 : ibc + 1;                         \
    asm volatile("" ::: "memory");                                              \
  } while (0)

  if constexpr (NC == 64){
    LDB(b0, 0); LDB(b1, 1);
    stageA(0, 0); stageA(1, 1); stageA(2, 2);
    SUB(0, b0, b2, 5);
    SUB(1, b1, b3, 7);
    SUB(2, b2, b0, 7);
    SUB(3, b3, b1, 7);
    #pragma unroll 1
    for (int tb = 4; tb < 60; tb += 4){
      SUB(tb + 0, b0, b2, 7);
      SUB(tb + 1, b1, b3, 7);
      SUB(tb + 2, b2, b0, 7);
      SUB(tb + 3, b3, b1, 7);
    }
    SUB(60, b0, b2, 7);
    SUB(61, b1, b3, 6);
    SUB(62, b2, b0, 3);
    SUB(63, b3, b1, 0);
  } else {
    LDB(b0, 0);
    stageA(0, 0); stageA(1, 1); stageA(2, 2);
    SUB(0, b0, b1, 7);
    SUB(1, b1, b0, 6);
    SUB(2, b0, b1, 6);
    SUB(3, b1, b0, 6);
    #pragma unroll 1
    for (int tb = 4; tb < 60; tb += 4){
      SUB(tb + 0, b0, b1, 6);
      SUB(tb + 1, b1, b0, 6);
      SUB(tb + 2, b0, b1, 6);
      SUB(tb + 3, b1, b0, 6);
    }
    SUB(60, b0, b1, 6);
    SUB(61, b1, b0, 5);
    SUB(62, b0, b1, 4);
    SUB(63, b1, b0, 0);
  }
  #undef SUB

  // ---- fused epilogue: C/D layout col = lane&15 (r0), row = hq*4 + j ----
  const bool isScat = (NC == 64) || (w >= 2);
  if (isScat){
    const int wS = (NC == 64) ? w : (w - 2);
    #pragma unroll
    for (int mi = 0; mi < 2; ++mi){
      const int rb = m0 + mi * 16 + hq * 4;
      const size_t rowb = (size_t)b * NN + rb;
      float4 dv4 = *(const float4*)(dinv + (size_t)b * NN + rb);
      #pragma unroll
      for (int ni = 0; ni < NF; ++ni){
        const int cs = wS * 16 * NF + ni * 16 + r0;   // local scat col 0..63
        float pn[4];
        #pragma unroll
        for (int j = 0; j < 4; ++j){
          float pv = sprev[(rowb + j) * 64 + cs];
          pn[j] = 0.5f * (pv + acc[mi][ni][j]);
          P[(rowb + j) * 64 + cs] = pn[j];
        }
        if (snap){
          #pragma unroll
          for (int j = 0; j < 4; ++j) snap[(rowb + j) * 64 + cs] = pn[j];
        }
        if (writeVtS){
          const int ct = 4 + wS * NF + ni;
          const int tp = rb >> 6, kkp = (rb >> 5) & 1;
          const int lp = r0 + 16 * ((rb >> 3) & 3), hf = (rb >> 2) & 1;
          ushort4 vv = make_ushort4(f2bf(dv4.x * pn[0]), f2bf(dv4.y * pn[1]),
                                    f2bf(dv4.z * pn[2]), f2bf(dv4.w * pn[3]));
          *(ushort4*)(BtW + ((((size_t)b * 8 + ct) * 64 + tp) * 2 + kkp) * 512
                          + (lp << 3) + hf * 4) = vv;
        }
      }
    }
  }
  if constexpr (NC == 128){
    if (!isScat){                                     // gcn waves 0,1
      #pragma unroll
      for (int mi = 0; mi < 2; ++mi){
        const int rb = m0 + mi * 16 + hq * 4;
        const size_t rowb = (size_t)b * NN + rb;
        float4 dq4 = *(const float4*)(dsq + (size_t)b * NN + rb);
        #pragma unroll
        for (int ni = 0; ni < NF; ++ni){
          const int cg = w * 16 * NF + ni * 16 + r0;  // gcn col 0..63
          float hn[4];
          const float dq[4] = {dq4.x, dq4.y, dq4.z, dq4.w};
          #pragma unroll
          for (int j = 0; j < 4; ++j){
            float hv = gprev[(rowb + j) * 64 + cg];
            hn[j] = (acc[mi][ni][j] + dq[j] * hv) * dq[j];
            gout[(rowb + j) * 64 + cg] = hn[j];
          }
          if (writeVtG){
            const int ct = w * NF + ni;
            const int tp = rb >> 6, kkp = (rb >> 5) & 1;
            const int lp = r0 + 16 * ((rb >> 3) & 3), hf = (rb >> 2) & 1;
            ushort4 vv = make_ushort4(f2bf(dq[0] * hn[0]), f2bf(dq[1] * hn[1]),
                                      f2bf(dq[2] * hn[2]), f2bf(dq[3] * hn[3]));
            *(ushort4*)(BtW + ((((size_t)b * 8 + ct) * 64 + tp) * 2 + kkp) * 512
                            + (lp << 3) + hf * 4) = vv;
          }
        }
      }
    }
  }
}

// ---------------- attention over 6 branches + 2-layer MLP ----------------
__global__ __launch_bounds__(256) void k_attn(
    const float* __restrict__ X,  const float* __restrict__ hA, const float* __restrict__ hA2,
    const float* __restrict__ U1, const float* __restrict__ U2, const float* __restrict__ U4,
    const float* __restrict__ U8, const float* __restrict__ W1, const float* __restrict__ b1,
    const float* __restrict__ W2, const float* __restrict__ b2, const float* __restrict__ av,
    const int* __restrict__ momp, float* __restrict__ out)
{
  __shared__ float W1s[64][65], W2s[64][65];
  __shared__ float a1s[64], a2s[64], b1s[64], b2s[64];
  __shared__ float hp[4][64], o1[4][64];
  const int tid = threadIdx.x;
  for (int e = tid; e < 4096; e += 256){
    W1s[e >> 6][e & 63] = W1[e];
    W2s[e >> 6][e & 63] = W2[e];
  }
  if (tid < 64){ a1s[tid] = av[tid]; a2s[tid] = av[64 + tid]; b1s[tid] = b1[tid]; b2s[tid] = b2[tid]; }
  __syncthreads();
  const int w = tid >> 6, l = tid & 63;
  size_t row = (size_t)blockIdx.x * 4 + w;
  size_t off = row * 64 + l;
  float x  = X[off];
  float u1 = U1[off], u2 = U2[off], u4 = U4[off], u8 = U8[off];
  float br[6];
  br[0] = leaky01(hA[off]);
  br[1] = leaky01(hA2[off]);
  float d1 = fabsf(x - u1), d2 = fabsf(u1 - u2), d3 = fabsf(u2 - u4), d4 = fabsf(u4 - u8);
  int mom = *momp;
  if (mom == 1){ br[2] = d1; br[3] = d2; br[4] = d3; br[5] = d4; }
  else {
    float m = (float)mom;
    br[2] = powf(d1, m); br[3] = powf(d2, m); br[4] = powf(d3, m); br[5] = powf(d4, m);
  }
  float v = fmaxf(x, 0.f) * a1s[l];
  for (int o = 32; o; o >>= 1) v += __shfl_xor(v, o);
  float base = v;
  float e[6];
  #pragma unroll
  for (int k = 0; k < 6; ++k){
    float t = fmaxf(br[k], 0.f) * a2s[l];
    for (int o = 32; o; o >>= 1) t += __shfl_xor(t, o);
    e[k] = base + t;
  }
  float mx = e[0];
  #pragma unroll
  for (int k = 1; k < 6; ++k) mx = fmaxf(mx, e[k]);
  float s = 0.f, att[6];
  #pragma unroll
  for (int k = 0; k < 6; ++k){ att[k] = expf(e[k] - mx); s += att[k]; }
  float inv = 1.0f / (6.0f * s);
  float hpv = 0.f;
  #pragma unroll
  for (int k = 0; k < 6; ++k) hpv += att[k] * br[k];
  hpv *= inv;
  hp[w][l] = hpv;
  __syncthreads();
  float acc = b1s[l];
  #pragma unroll 8
  for (int c = 0; c < 64; ++c) acc += hp[w][c] * W1s[l][c];
  o1[w][l] = leaky01(acc);
  __syncthreads();
  float acc2 = b2s[l];
  #pragma unroll 8
  for (int c = 0; c < 64; ++c) acc2 += o1[w][c] * W2s[l][c];
  out[off] = leaky01(acc2);
}

// ---------------- workspace layout ----------------
static constexpr size_t OFF_ADJB = 0;                                   // bf16 A staging image
static constexpr size_t OFF_VTA  = OFF_ADJB + (size_t)BB * NN * NN * 2; // bf16 frag-order B
static constexpr size_t OFF_VTB  = OFF_VTA  + (size_t)BB * 128 * NN * 2;
static constexpr size_t OFF_HA   = OFF_VTB  + (size_t)BB * 128 * NN * 2;
static constexpr size_t OFF_HA2  = OFF_HA   + (size_t)BB * NN * 64 * 4;
static constexpr size_t OFF_P    = OFF_HA2  + (size_t)BB * NN * 64 * 4;
static constexpr size_t OFF_U1   = OFF_P    + (size_t)BB * NN * 64 * 4;
static constexpr size_t OFF_U2   = OFF_U1   + (size_t)BB * NN * 64 * 4;
static constexpr size_t OFF_U4   = OFF_U2   + (size_t)BB * NN * 64 * 4;
static constexpr size_t OFF_U8   = OFF_U4   + (size_t)BB * NN * 64 * 4;
static constexpr size_t OFF_DINV = OFF_U8   + (size_t)BB * NN * 64 * 4;
static constexpr size_t OFF_DS   = OFF_DINV + (size_t)BB * NN * 4;
static constexpr size_t WS_NEED  = OFF_DS   + (size_t)BB * NN * 4;

extern "C" void kernel_launch(void* const* d_in, const int* in_sizes, int n_in,
                              void* d_out, int out_size, void* d_ws, size_t ws_size,
                              hipStream_t stream)
{
  const float* X   = (const float*)d_in[0];
  const float* adj = (const float*)d_in[1];
  const float* W1  = (const float*)d_in[2];
  const float* b1  = (const float*)d_in[3];
  const float* W2  = (const float*)d_in[4];
  const float* b2  = (const float*)d_in[5];
  const float* av  = (const float*)d_in[6];
  const int*  momp = (const int*)d_in[7];
  float* out = (float*)d_out;

  if (ws_size < WS_NEED){
    fprintf(stderr, "kernel_launch: workspace too small: %zu < %zu\n", ws_size, WS_NEED);
    return;
  }
  char* w = (char*)d_ws;
  unsigned short* At  = (unsigned short*)(w + OFF_ADJB);
  unsigned short* vtA = (unsigned short*)(w + OFF_VTA);
  unsigned short* vtB = (unsigned short*)(w + OFF_VTB);
  float* hA   = (float*)(w + OFF_HA);
  float* hA2  = (float*)(w + OFF_HA2);
  float* P    = (float*)(w + OFF_P);
  float* U1   = (float*)(w + OFF_U1);
  float* U2   = (float*)(w + OFF_U2);
  float* U4   = (float*)(w + OFF_U4);
  float* U8   = (float*)(w + OFF_U8);
  float* dinv = (float*)(w + OFF_DINV);
  float* dsq  = (float*)(w + OFF_DS);

  k_convert<<<1024, 256, 0, stream>>>(adj, At, dinv, dsq);
  dim3 tg64(NN / 64, BB);
  k_prep<<<tg64, 256, 0, stream>>>(X, dinv, dsq, vtA);

  // pass 1: dual RHS (gcn: dsq*X -> hA, scat: dinv*X -> P,U1); writes vtB (both halves)
  k_gemm_fused<128><<<1024, 256, 0, stream>>>(At, vtA, 0,
      X, P, U1, dinv, 1, X, hA, dsq, 1, vtB);
  // pass 2: dual RHS (gcn -> hA2, scat -> P,U2); writes vtA (scat half)
  k_gemm_fused<128><<<1024, 256, 0, stream>>>(At, vtB, 0,
      P, P, U2, dinv, 1, hA, hA2, dsq, 0, vtA);
  // passes 3..8: scattering only, alternate vtA/vtB
  unsigned short* vr = vtA;
  unsigned short* vw = vtB;
  for (int k = 3; k <= 8; ++k){
    float* snap = (k == 4) ? U4 : nullptr;
    float* pdst = (k == 8) ? U8 : P;
    k_gemm_fused<64><<<1024, 256, 0, stream>>>(At, vr, 4,
        P, pdst, snap, dinv, (k < 8) ? 1 : 0, nullptr, nullptr, nullptr, 0, vw);
    unsigned short* t = vr; vr = vw; vw = t;
  }

  k_attn<<<BB * NN / 4, 256, 0, stream>>>(X, hA, hA2, U1, U2, U4, U8,
                                          W1, b1, W2, b2, av, momp, out);
}

// Round 12
// 696.677 us; speedup vs baseline: 1.4331x; 1.1237x over previous
//
#include <hip/hip_runtime.h>
#include <hip/hip_bf16.h>
#include <cstdio>
#include <cstdint>

#define BB 8
#define NN 4096
#define FF 64

typedef __attribute__((ext_vector_type(8))) short bf16x8;
typedef __attribute__((ext_vector_type(4))) float f32x4;

__device__ __forceinline__ unsigned short f2bf(float f){
  unsigned int u = __float_as_uint(f);
  u += 0x7FFFu + ((u >> 16) & 1u);           // round-to-nearest-even
  return (unsigned short)(u >> 16);
}

__device__ __forceinline__ float leaky01(float x){ return x > 0.f ? x : 0.01f * x; }

// ================= layouts =================
// A staging image (BM=64): At[bid][t(64)][(r*8+g)*8+j] =
//   bf16(adj[b][m0 + r][t*64 + ((g^(r&7))<<3) + j]),  r in 0..63, bid = b + 8*mt, m0 = mt*64.
//   One contiguous 512 KB stream per block; tile t = 8 KB staged by 2 global_load_lds/thread.
// B fragment order (R9-proven): Bt[b][ct(8)][t(64)][kk(2)][l(64)][j(8)]
//   element = scale * H[row = t*64 + kk*32 + (l>>4)*8 + j][col = ct*16 + (l&15)]
//   ct 0..3 = gcn half (cols 0..63), ct 4..7 = scat half

// ---------------- pass 0: fp32 adj -> A staging image + row sums ----------------
__global__ __launch_bounds__(256) void k_convert(const float* __restrict__ adj,
    unsigned short* __restrict__ At, float* __restrict__ dinv, float* __restrict__ dsq)
{
  const int bid = blockIdx.x;              // 512 blocks; b = bid&7 (XCD-aligned)
  const int b = bid & 7, mt = bid >> 3, m0 = mt * 64;
  const int tid = threadIdx.x;
  const int r = tid >> 3, g = tid & 7;     // r in 0..31; rows r and r+32 per thread
  const float* src0 = adj + ((size_t)b * NN + m0 + r) * NN + ((g ^ (r & 7)) << 3);
  const float* src1 = src0 + (size_t)32 * NN;            // (r+32)&7 == r&7
  unsigned short* dst0 = At + (size_t)bid * 262144 + (((r)      * 8 + g) << 3);
  unsigned short* dst1 = At + (size_t)bid * 262144 + (((r + 32) * 8 + g) << 3);
  float s0 = 0.f, s1 = 0.f;
  for (int t = 0; t < 64; ++t){
    const float* p0 = src0 + t * 64;
    float4 a = *(const float4*)p0, c = *(const float4*)(p0 + 4);
    s0 += ((a.x + a.y) + (a.z + a.w)) + ((c.x + c.y) + (c.z + c.w));
    bf16x8 v;
    v[0]=(short)f2bf(a.x); v[1]=(short)f2bf(a.y); v[2]=(short)f2bf(a.z); v[3]=(short)f2bf(a.w);
    v[4]=(short)f2bf(c.x); v[5]=(short)f2bf(c.y); v[6]=(short)f2bf(c.z); v[7]=(short)f2bf(c.w);
    *(bf16x8*)(dst0 + (size_t)t * 4096) = v;
    const float* p1 = src1 + t * 64;
    float4 e = *(const float4*)p1, h = *(const float4*)(p1 + 4);
    s1 += ((e.x + e.y) + (e.z + e.w)) + ((h.x + h.y) + (h.z + h.w));
    bf16x8 u;
    u[0]=(short)f2bf(e.x); u[1]=(short)f2bf(e.y); u[2]=(short)f2bf(e.z); u[3]=(short)f2bf(e.w);
    u[4]=(short)f2bf(h.x); u[5]=(short)f2bf(h.y); u[6]=(short)f2bf(h.z); u[7]=(short)f2bf(h.w);
    *(bf16x8*)(dst1 + (size_t)t * 4096) = u;
  }
  s0 += __shfl_xor(s0, 1); s0 += __shfl_xor(s0, 2); s0 += __shfl_xor(s0, 4);
  s1 += __shfl_xor(s1, 1); s1 += __shfl_xor(s1, 2); s1 += __shfl_xor(s1, 4);
  if (g == 0){
    dinv[(size_t)b * NN + m0 + r] = 1.0f / s0;
    dsq [(size_t)b * NN + m0 + r] = 1.0f / sqrtf(s0 + 1.0f);
    dinv[(size_t)b * NN + m0 + 32 + r] = 1.0f / s1;
    dsq [(size_t)b * NN + m0 + 32 + r] = 1.0f / sqrtf(s1 + 1.0f);
  }
}

// ---------------- initial RHS in fragment order: ct0-3 = dsq*X, ct4-7 = dinv*X ----------
__global__ __launch_bounds__(256) void k_prep(const float* __restrict__ X,
    const float* __restrict__ dinv, const float* __restrict__ dsq,
    unsigned short* __restrict__ Bt)
{
  const int b = blockIdx.y, n0 = blockIdx.x * 64, tid = threadIdx.x;
  __shared__ unsigned short tg[64][68], ts[64][68];
  #pragma unroll
  for (int i = 0; i < 4; ++i){
    int idx = i * 256 + tid, n = idx >> 4, c4 = (idx & 15) * 4;
    size_t rb = (size_t)b * NN + n0 + n;
    float4 x = *(const float4*)(X + rb * 64 + c4);
    float di = dinv[b * NN + n0 + n], dv = dsq[b * NN + n0 + n];
    tg[c4 + 0][n] = f2bf(dv * x.x); tg[c4 + 1][n] = f2bf(dv * x.y);
    tg[c4 + 2][n] = f2bf(dv * x.z); tg[c4 + 3][n] = f2bf(dv * x.w);
    ts[c4 + 0][n] = f2bf(di * x.x); ts[c4 + 1][n] = f2bf(di * x.y);
    ts[c4 + 2][n] = f2bf(di * x.z); ts[c4 + 3][n] = f2bf(di * x.w);
  }
  __syncthreads();
  const int t = n0 >> 6;
  #pragma unroll
  for (int it = 0; it < 8; ++it){
    int idx = it * 256 + tid;
    int half = idx & 1, l = (idx >> 1) & 63, kk = (idx >> 7) & 1, ct = (idx >> 8) & 7;
    int cl = ((ct & 3) << 4) + (l & 15);
    int nl = kk * 32 + ((l >> 4) << 3) + half * 4;
    ushort4 v = (ct < 4) ? *(const ushort4*)&tg[cl][nl] : *(const ushort4*)&ts[cl][nl];
    *(ushort4*)(Bt + ((((size_t)b * 8 + ct) * 64 + t) * 2 + kk) * 512 + (l << 3) + half * 4) = v;
  }
}

// ---- fused GEMM + epilogue: BM=64, 4-deep A-LDS (stage distance 2), B reg-direct ----
template<int NC>
__global__ __launch_bounds__(256, 2) void k_gemm_fused(
    const unsigned short* __restrict__ At,
    const unsigned short* __restrict__ BtR, int ct0,
    const float* __restrict__ sprev, float* __restrict__ P, float* __restrict__ snap,
    const float* __restrict__ dinv, int writeVtS,
    const float* __restrict__ gprev, float* __restrict__ gout,
    const float* __restrict__ dsq, int writeVtG,
    unsigned short* __restrict__ BtW)
{
  constexpr int NF = NC / 64;
  __shared__ __align__(16) unsigned short As[4][64 * 64];   // 64 KB
  const int bid = blockIdx.x;                                // 512 blocks
  const int b = bid & 7, mt = bid >> 3, m0 = mt * 64;
  const int tid = threadIdx.x;
  const int w = tid >> 6, l = tid & 63;
  const int r0 = l & 15, hq = l >> 4, sw = r0 & 7;
  const unsigned short* Atile = At + (size_t)bid * 262144;
  const unsigned short* Bb0 = BtR + (((size_t)b * 8 + ct0 + w * NF) * 64) * 1024 + (l << 3);
  const unsigned short* Bb1 = Bb0 + (size_t)64 * 1024;       // ni=1 (NC==128 only)

  auto stageA = [&](int buf, int t){
    const unsigned short* gp0 = Atile + (size_t)t * 4096 + (tid << 3);
    __builtin_amdgcn_global_load_lds((const __attribute__((address_space(1))) void*)gp0,
        (__attribute__((address_space(3))) void*)(&As[buf][tid << 3]), 16, 0, 0);
    __builtin_amdgcn_global_load_lds((const __attribute__((address_space(1))) void*)(gp0 + 2048),
        (__attribute__((address_space(3))) void*)(&As[buf][(256 + tid) << 3]), 16, 0, 0);
  };

  f32x4 acc[4][NF];
  #pragma unroll
  for (int mi = 0; mi < 4; ++mi)
    #pragma unroll
    for (int ni = 0; ni < NF; ++ni)
      #pragma unroll
      for (int j = 0; j < 4; ++j) acc[mi][ni][j] = 0.f;

  #define VMW(N) asm volatile("s_waitcnt vmcnt(" #N ")" ::: "memory")
  #define BARX do{ __builtin_amdgcn_s_barrier(); asm volatile("" ::: "memory"); }while(0)

  if constexpr (NC == 64){
    bf16x8 b0[2], b1[2], b2[2], b3[2];
    #define LDB1(PB, T) do{ \
      PB[0] = *(const bf16x8*)(Bb0 + (size_t)(T) * 1024); \
      PB[1] = *(const bf16x8*)(Bb0 + (size_t)(T) * 1024 + 512); }while(0)
    #define CMP64(IB, PB) do{ \
      const unsigned short* asb = &As[(IB)][0]; \
      _Pragma("unroll") for (int kk = 0; kk < 2; ++kk){ \
        const int g8 = ((kk * 4 + hq) ^ sw) << 3; \
        _Pragma("unroll") for (int mi = 0; mi < 4; ++mi){ \
          bf16x8 af = *(const bf16x8*)&asb[(mi * 16 + r0) * 64 + g8]; \
          acc[mi][0] = __builtin_amdgcn_mfma_f32_16x16x32_bf16(af, PB[kk], acc[mi][0], 0, 0, 0); \
        } } }while(0)
    #define SUB64(T, BC, BL, N) do{ \
      if ((T) + 2 < 64){ LDB1(BL, (T) + 2); stageA(((T) + 2) & 3, (T) + 2); } \
      VMW(N); BARX; CMP64((T) & 3, BC); asm volatile("" ::: "memory"); }while(0)

    stageA(0, 0); stageA(1, 1);
    LDB1(b0, 0); LDB1(b1, 1);
    SUB64(0, b0, b2, 6);
    SUB64(1, b1, b3, 8);
    #pragma unroll 1
    for (int T0 = 2; T0 <= 58; T0 += 4){
      SUB64(T0 + 0, b2, b0, 8);
      SUB64(T0 + 1, b3, b1, 8);
      SUB64(T0 + 2, b0, b2, 8);
      SUB64(T0 + 3, b1, b3, 8);
    }
    SUB64(62, b2, b0, 4);
    SUB64(63, b3, b1, 0);
  } else {
    bf16x8 b0[2][2], b1[2][2];
    #define LDB2(PB, T) do{ \
      PB[0][0] = *(const bf16x8*)(Bb0 + (size_t)(T) * 1024); \
      PB[0][1] = *(const bf16x8*)(Bb0 + (size_t)(T) * 1024 + 512); \
      PB[1][0] = *(const bf16x8*)(Bb1 + (size_t)(T) * 1024); \
      PB[1][1] = *(const bf16x8*)(Bb1 + (size_t)(T) * 1024 + 512); }while(0)
    #define CMP128(IB, PB) do{ \
      const unsigned short* asb = &As[(IB)][0]; \
      _Pragma("unroll") for (int kk = 0; kk < 2; ++kk){ \
        const int g8 = ((kk * 4 + hq) ^ sw) << 3; \
        _Pragma("unroll") for (int mi = 0; mi < 4; ++mi){ \
          bf16x8 af = *(const bf16x8*)&asb[(mi * 16 + r0) * 64 + g8]; \
          acc[mi][0] = __builtin_amdgcn_mfma_f32_16x16x32_bf16(af, PB[0][kk], acc[mi][0], 0, 0, 0); \
          acc[mi][1] = __builtin_amdgcn_mfma_f32_16x16x32_bf16(af, PB[1][kk], acc[mi][1], 0, 0, 0); \
        } } }while(0)
    #define SUB128(T, BC, BL, N) do{ \
      if ((T) + 1 < 64) LDB2(BL, (T) + 1); \
      if ((T) + 2 < 64) stageA(((T) + 2) & 3, (T) + 2); \
      VMW(N); BARX; CMP128((T) & 3, BC); asm volatile("" ::: "memory"); }while(0)

    stageA(0, 0); stageA(1, 1);
    LDB2(b0, 0);
    SUB128(0, b0, b1, 6);
    #pragma unroll 1
    for (int T0 = 1; T0 <= 59; T0 += 2){
      SUB128(T0 + 0, b1, b0, 8);
      SUB128(T0 + 1, b0, b1, 8);
    }
    SUB128(61, b1, b0, 8);
    SUB128(62, b0, b1, 6);
    SUB128(63, b1, b0, 0);
  }

  // ---- fused epilogue: C/D layout col = lane&15 (r0), row = hq*4 + j ----
  const bool isScat = (NC == 64) || (w >= 2);
  if (isScat){
    const int wS = (NC == 64) ? w : (w - 2);
    #pragma unroll
    for (int mi = 0; mi < 4; ++mi){
      const int rb = m0 + mi * 16 + hq * 4;
      const size_t rowb = (size_t)b * NN + rb;
      float4 dv4 = *(const float4*)(dinv + (size_t)b * NN + rb);
      #pragma unroll
      for (int ni = 0; ni < NF; ++ni){
        const int cs = wS * 16 * NF + ni * 16 + r0;   // local scat col 0..63
        float pn[4];
        #pragma unroll
        for (int j = 0; j < 4; ++j){
          float pv = sprev[(rowb + j) * 64 + cs];
          pn[j] = 0.5f * (pv + acc[mi][ni][j]);
          P[(rowb + j) * 64 + cs] = pn[j];
        }
        if (snap){
          #pragma unroll
          for (int j = 0; j < 4; ++j) snap[(rowb + j) * 64 + cs] = pn[j];
        }
        if (writeVtS){
          const int ct = 4 + wS * NF + ni;
          const int tp = rb >> 6, kkp = (rb >> 5) & 1;
          const int lp = r0 + 16 * ((rb >> 3) & 3), hf = (rb >> 2) & 1;
          ushort4 vv = make_ushort4(f2bf(dv4.x * pn[0]), f2bf(dv4.y * pn[1]),
                                    f2bf(dv4.z * pn[2]), f2bf(dv4.w * pn[3]));
          *(ushort4*)(BtW + ((((size_t)b * 8 + ct) * 64 + tp) * 2 + kkp) * 512
                          + (lp << 3) + hf * 4) = vv;
        }
      }
    }
  }
  if constexpr (NC == 128){
    if (!isScat){                                     // gcn waves 0,1
      #pragma unroll
      for (int mi = 0; mi < 4; ++mi){
        const int rb = m0 + mi * 16 + hq * 4;
        const size_t rowb = (size_t)b * NN + rb;
        float4 dq4 = *(const float4*)(dsq + (size_t)b * NN + rb);
        #pragma unroll
        for (int ni = 0; ni < NF; ++ni){
          const int cg = w * 16 * NF + ni * 16 + r0;  // gcn col 0..63
          float hn[4];
          const float dq[4] = {dq4.x, dq4.y, dq4.z, dq4.w};
          #pragma unroll
          for (int j = 0; j < 4; ++j){
            float hv = gprev[(rowb + j) * 64 + cg];
            hn[j] = (acc[mi][ni][j] + dq[j] * hv) * dq[j];
            gout[(rowb + j) * 64 + cg] = hn[j];
          }
          if (writeVtG){
            const int ct = w * NF + ni;
            const int tp = rb >> 6, kkp = (rb >> 5) & 1;
            const int lp = r0 + 16 * ((rb >> 3) & 3), hf = (rb >> 2) & 1;
            ushort4 vv = make_ushort4(f2bf(dq[0] * hn[0]), f2bf(dq[1] * hn[1]),
                                      f2bf(dq[2] * hn[2]), f2bf(dq[3] * hn[3]));
            *(ushort4*)(BtW + ((((size_t)b * 8 + ct) * 64 + tp) * 2 + kkp) * 512
                            + (lp << 3) + hf * 4) = vv;
          }
        }
      }
    }
  }
}

// ---------------- attention over 6 branches + 2-layer MLP ----------------
__global__ __launch_bounds__(256) void k_attn(
    const float* __restrict__ X,  const float* __restrict__ hA, const float* __restrict__ hA2,
    const float* __restrict__ U1, const float* __restrict__ U2, const float* __restrict__ U4,
    const float* __restrict__ U8, const float* __restrict__ W1, const float* __restrict__ b1,
    const float* __restrict__ W2, const float* __restrict__ b2, const float* __restrict__ av,
    const int* __restrict__ momp, float* __restrict__ out)
{
  __shared__ float W1s[64][65], W2s[64][65];
  __shared__ float a1s[64], a2s[64], b1s[64], b2s[64];
  __shared__ float hp[4][64], o1[4][64];
  const int tid = threadIdx.x;
  for (int e = tid; e < 4096; e += 256){
    W1s[e >> 6][e & 63] = W1[e];
    W2s[e >> 6][e & 63] = W2[e];
  }
  if (tid < 64){ a1s[tid] = av[tid]; a2s[tid] = av[64 + tid]; b1s[tid] = b1[tid]; b2s[tid] = b2[tid]; }
  __syncthreads();
  const int w = tid >> 6, l = tid & 63;
  size_t row = (size_t)blockIdx.x * 4 + w;
  size_t off = row * 64 + l;
  float x  = X[off];
  float u1 = U1[off], u2 = U2[off], u4 = U4[off], u8 = U8[off];
  float br[6];
  br[0] = leaky01(hA[off]);
  br[1] = leaky01(hA2[off]);
  float d1 = fabsf(x - u1), d2 = fabsf(u1 - u2), d3 = fabsf(u2 - u4), d4 = fabsf(u4 - u8);
  int mom = *momp;
  if (mom == 1){ br[2] = d1; br[3] = d2; br[4] = d3; br[5] = d4; }
  else {
    float m = (float)mom;
    br[2] = powf(d1, m); br[3] = powf(d2, m); br[4] = powf(d3, m); br[5] = powf(d4, m);
  }
  float v = fmaxf(x, 0.f) * a1s[l];
  for (int o = 32; o; o >>= 1) v += __shfl_xor(v, o);
  float base = v;
  float e[6];
  #pragma unroll
  for (int k = 0; k < 6; ++k){
    float t = fmaxf(br[k], 0.f) * a2s[l];
    for (int o = 32; o; o >>= 1) t += __shfl_xor(t, o);
    e[k] = base + t;
  }
  float mx = e[0];
  #pragma unroll
  for (int k = 1; k < 6; ++k) mx = fmaxf(mx, e[k]);
  float s = 0.f, att[6];
  #pragma unroll
  for (int k = 0; k < 6; ++k){ att[k] = expf(e[k] - mx); s += att[k]; }
  float inv = 1.0f / (6.0f * s);
  float hpv = 0.f;
  #pragma unroll
  for (int k = 0; k < 6; ++k) hpv += att[k] * br[k];
  hpv *= inv;
  hp[w][l] = hpv;
  __syncthreads();
  float acc = b1s[l];
  #pragma unroll 8
  for (int c = 0; c < 64; ++c) acc += hp[w][c] * W1s[l][c];
  o1[w][l] = leaky01(acc);
  __syncthreads();
  float acc2 = b2s[l];
  #pragma unroll 8
  for (int c = 0; c < 64; ++c) acc2 += o1[w][c] * W2s[l][c];
  out[off] = leaky01(acc2);
}

// ---------------- workspace layout ----------------
static constexpr size_t OFF_ADJB = 0;                                   // bf16 A staging image
static constexpr size_t OFF_VTA  = OFF_ADJB + (size_t)BB * NN * NN * 2; // bf16 frag-order B
static constexpr size_t OFF_VTB  = OFF_VTA  + (size_t)BB * 128 * NN * 2;
static constexpr size_t OFF_HA   = OFF_VTB  + (size_t)BB * 128 * NN * 2;
static constexpr size_t OFF_HA2  = OFF_HA   + (size_t)BB * NN * 64 * 4;
static constexpr size_t OFF_P    = OFF_HA2  + (size_t)BB * NN * 64 * 4;
static constexpr size_t OFF_U1   = OFF_P    + (size_t)BB * NN * 64 * 4;
static constexpr size_t OFF_U2   = OFF_U1   + (size_t)BB * NN * 64 * 4;
static constexpr size_t OFF_U4   = OFF_U2   + (size_t)BB * NN * 64 * 4;
static constexpr size_t OFF_U8   = OFF_U4   + (size_t)BB * NN * 64 * 4;
static constexpr size_t OFF_DINV = OFF_U8   + (size_t)BB * NN * 64 * 4;
static constexpr size_t OFF_DS   = OFF_DINV + (size_t)BB * NN * 4;
static constexpr size_t WS_NEED  = OFF_DS   + (size_t)BB * NN * 4;

extern "C" void kernel_launch(void* const* d_in, const int* in_sizes, int n_in,
                              void* d_out, int out_size, void* d_ws, size_t ws_size,
                              hipStream_t stream)
{
  const float* X   = (const float*)d_in[0];
  const float* adj = (const float*)d_in[1];
  const float* W1  = (const float*)d_in[2];
  const float* b1  = (const float*)d_in[3];
  const float* W2  = (const float*)d_in[4];
  const float* b2  = (const float*)d_in[5];
  const float* av  = (const float*)d_in[6];
  const int*  momp = (const int*)d_in[7];
  float* out = (float*)d_out;

  if (ws_size < WS_NEED){
    fprintf(stderr, "kernel_launch: workspace too small: %zu < %zu\n", ws_size, WS_NEED);
    return;
  }
  char* w = (char*)d_ws;
  unsigned short* At  = (unsigned short*)(w + OFF_ADJB);
  unsigned short* vtA = (unsigned short*)(w + OFF_VTA);
  unsigned short* vtB = (unsigned short*)(w + OFF_VTB);
  float* hA   = (float*)(w + OFF_HA);
  float* hA2  = (float*)(w + OFF_HA2);
  float* P    = (float*)(w + OFF_P);
  float* U1   = (float*)(w + OFF_U1);
  float* U2   = (float*)(w + OFF_U2);
  float* U4   = (float*)(w + OFF_U4);
  float* U8   = (float*)(w + OFF_U8);
  float* dinv = (float*)(w + OFF_DINV);
  float* dsq  = (float*)(w + OFF_DS);

  k_convert<<<512, 256, 0, stream>>>(adj, At, dinv, dsq);
  dim3 tg64(NN / 64, BB);
  k_prep<<<tg64, 256, 0, stream>>>(X, dinv, dsq, vtA);

  // pass 1: dual RHS (gcn: dsq*X -> hA, scat: dinv*X -> P,U1); writes vtB (both halves)
  k_gemm_fused<128><<<512, 256, 0, stream>>>(At, vtA, 0,
      X, P, U1, dinv, 1, X, hA, dsq, 1, vtB);
  // pass 2: dual RHS (gcn -> hA2, scat -> P,U2); writes vtA (scat half)
  k_gemm_fused<128><<<512, 256, 0, stream>>>(At, vtB, 0,
      P, P, U2, dinv, 1, hA, hA2, dsq, 0, vtA);
  // passes 3..8: scattering only, alternate vtA/vtB
  unsigned short* vr = vtA;
  unsigned short* vw = vtB;
  for (int k = 3; k <= 8; ++k){
    float* snap = (k == 4) ? U4 : nullptr;
    float* pdst = (k == 8) ? U8 : P;
    k_gemm_fused<64><<<512, 256, 0, stream>>>(At, vr, 4,
        P, pdst, snap, dinv, (k < 8) ? 1 : 0, nullptr, nullptr, nullptr, 0, vw);
    unsigned short* t = vr; vr = vw; vw = t;
  }

  k_attn<<<BB * NN / 4, 256, 0, stream>>>(X, hA, hA2, U1, U2, U4, U8,
                                          W1, b1, W2, b2, av, momp, out);
}